// Round 6
// baseline (80.230 us; speedup 1.0000x reference)
//
#include <hip/hip_runtime.h>
#include <math.h>

// E8S codebook quantization via bf16 MFMA, exact 3-way split, single pass.
//   scores[r][c] = 2*X[r]·G[c] - ||G[c]||^2 ; idx = first-argmax over c.
// Exactness: G coords are multiples of 0.25 (exact bf16); 2*X = h+m+l exact
// 3-term bf16 split; ||g||^2 is a multiple of 0.5 < 16 -> exact bf16, folded
// into the MFMA K-reduction as a 9th term paired with -1.0 on the X side
// (K-group 3). C operand = 0. One mfma_f32_16x16x32_bf16 => biased 16x16
// score tile. Swapped operands (A=G, B=X): each lane's 4 D regs = 4 codewords
// of ONE row. Branchless 12-op argmax tracking; global merge via packed u64
// atomicMax (ordered-score<<32 | ~idx) == np.argmax first-max semantics.
// R6: asm-pin xf fragments (compiler was rematerializing the loads every
// iteration -> hidden global traffic + stalls, VGPR_Count=36 proved it).

typedef short short8 __attribute__((ext_vector_type(8)));
typedef float f32x4  __attribute__((ext_vector_type(4)));

constexpr int NROWS  = 8192;
constexpr int NCW    = 55650;
constexpr int NTILE  = 3479;          // ceil(NCW/16)
constexpr int NCWP   = NTILE * 16;    // 55664 (pad scores ~ -3.4e38)
constexpr int NCHUNK = 128;           // codeword-tile chunks (grid.y)
constexpr int RB     = 16;            // row blocks of 512 rows (grid.x)

// workspace layout (bytes)
// Gb2: [NCWP][16] ushort — 0..7 = bf16 coords, 8 = bf16 gn, 9..15 = 0
constexpr size_t OFF_GB2 = 0;
constexpr size_t OFF_XS  = OFF_GB2 + (size_t)NCWP * 32;  // ushort Xs[NROWS*4*8]
constexpr size_t OFF_B   = OFF_XS  + (size_t)NROWS * 64; // u64 best[NROWS]

__device__ inline unsigned short bf16_rne(float f) {
  unsigned int u = __float_as_uint(f);
  unsigned int r = u + 0x7FFFu + ((u >> 16) & 1u);
  return (unsigned short)(r >> 16);
}
__device__ inline float bf16_f(unsigned short h) {
  return __uint_as_float(((unsigned int)h) << 16);
}
__device__ inline unsigned int enc_ord(float f) {  // monotonic float->uint
  unsigned int u = __float_as_uint(f);
  return (u & 0x80000000u) ? ~u : (u | 0x80000000u);
}

__global__ __launch_bounds__(256) void e8_prep(
    const float* __restrict__ X, const float* __restrict__ G,
    const float* __restrict__ GN, unsigned short* __restrict__ Gb2,
    unsigned short* __restrict__ Xs, unsigned long long* __restrict__ best) {
  int i = blockIdx.x * 256 + threadIdx.x;
  if (i < NCWP) {
    unsigned short* g = Gb2 + (size_t)i * 16;
    if (i < NCW) {
      for (int j = 0; j < 8; ++j) g[j] = bf16_rne(G[(size_t)i*8+j]);
      g[8] = bf16_rne(GN[i]);           // exact: multiple of 0.5, < 16
      for (int j = 9; j < 16; ++j) g[j] = 0;
    } else {
      for (int j = 0; j < 8; ++j) g[j] = 0;
      g[8] = 0x7F7F;                    // bf16 max finite -> score ~ -3.4e38
      for (int j = 9; j < 16; ++j) g[j] = 0;
    }
  } else if (i < NCWP + NROWS) {
    int r = i - NCWP;
    for (int j = 0; j < 8; ++j) {
      float s = 2.0f * X[(size_t)r*8+j];           // exact
      unsigned short h = bf16_rne(s);  float r1 = s  - bf16_f(h);  // exact
      unsigned short m = bf16_rne(r1); float r2 = r1 - bf16_f(m);  // exact
      unsigned short l = bf16_rne(r2);             // residual after 3 terms = 0
      Xs[((size_t)r*4 + 0)*8 + j] = h;
      Xs[((size_t)r*4 + 1)*8 + j] = m;
      Xs[((size_t)r*4 + 2)*8 + j] = l;
      Xs[((size_t)r*4 + 3)*8 + j] = (j == 0) ? (unsigned short)0xBF80 : 0; // -1.0
    }
    best[r] = 0ull;   // below enc_ord of any real score
  }
}

// Per block: 4 waves x 8 row-tiles = 512 rows, one chunk of ~27 codeword tiles.
// Lane roles: c = lane&15 (codeword-in-tile AND X-row-in-tile), kg = lane>>4.
// A-fragment: kg 0..2 read the coord slice (K-replication), kg 3 the gn slice.
__global__ __launch_bounds__(256, 4) void e8_main(
    const unsigned short* __restrict__ Gb2,
    const unsigned short* __restrict__ Xs,
    unsigned long long* __restrict__ best) {
  const int lane = threadIdx.x & 63;
  const int wave = threadIdx.x >> 6;
  const int c = lane & 15, kg = lane >> 4;
  const int rt0 = blockIdx.x * 32 + wave * 8;

  f32x4 xr[8];
#pragma unroll
  for (int t = 0; t < 8; ++t) {
    int row = (rt0 + t) * 16 + c;
    xr[t] = *reinterpret_cast<const f32x4*>(Xs + ((size_t)row*4 + kg)*8);
  }
#pragma unroll
  for (int t = 0; t < 8; ++t)
    asm volatile("" : "+v"(xr[t]));   // pin in VGPRs: loads can't rematerialize

  const int ct0 = (blockIdx.y * NTILE) / NCHUNK;
  const int ct1 = ((blockIdx.y + 1) * NTILE) / NCHUNK;

  float b[8]; int bi[8];
#pragma unroll
  for (int t = 0; t < 8; ++t) { b[t] = -INFINITY; bi[t] = 0; }

  const f32x4 cz = {0.f, 0.f, 0.f, 0.f};
  const unsigned short* gb = Gb2 + (size_t)c * 16 + (kg == 3 ? 8 : 0);

  for (int ct = ct0; ct < ct1; ++ct) {
    short8 af = *reinterpret_cast<const short8*>(gb + (size_t)ct * 256);
    const int i0 = ct * 4, i1 = i0 + 1, i2 = i0 + 2, i3 = i0 + 3;  // uniform
#pragma unroll
    for (int t = 0; t < 8; ++t) {
      f32x4 d = __builtin_amdgcn_mfma_f32_16x16x32_bf16(
          af, __builtin_bit_cast(short8, xr[t]), cz, 0, 0, 0);
      float m = fmaxf(fmaxf(d[0], d[1]), fmaxf(d[2], d[3]));
      int cand = i3;
      cand = (d[2] == m) ? i2 : cand;   // downward chain -> first slot wins
      cand = (d[1] == m) ? i1 : cand;
      cand = (d[0] == m) ? i0 : cand;
      bi[t] = (m > b[t]) ? cand : bi[t];  // strict > -> earliest tile wins
      b[t]  = fmaxf(b[t], m);
    }
  }

#pragma unroll
  for (int t = 0; t < 8; ++t) {
    const int gi = ((bi[t] >> 2) << 4) + kg * 4 + (bi[t] & 3);  // global cw idx
    unsigned long long key =
        ((unsigned long long)enc_ord(b[t]) << 32) | (unsigned int)(~gi);
    unsigned long long o = __shfl_xor(key, 16, 64); key = (o > key) ? o : key;
    o = __shfl_xor(key, 32, 64);                    key = (o > key) ? o : key;
    if (lane < 16) atomicMax(&best[(size_t)(rt0 + t) * 16 + c], key);
  }
}

__global__ __launch_bounds__(256) void e8_final(
    const float* __restrict__ G, const unsigned long long* __restrict__ best,
    float* __restrict__ out) {
  const int r = blockIdx.x * 256 + threadIdx.x;
  const int idx = (int)(~(unsigned int)(best[r] & 0xFFFFFFFFull));
  const float4* g = reinterpret_cast<const float4*>(G + (size_t)idx * 8);
  float4 v0 = g[0], v1 = g[1];
  float4* o = reinterpret_cast<float4*>(out + (size_t)r * 8);
  o[0] = v0; o[1] = v1;
  out[(size_t)NROWS * 8 + r] = (float)(idx - 32768);
}

extern "C" void kernel_launch(void* const* d_in, const int* in_sizes, int n_in,
                              void* d_out, int out_size, void* d_ws, size_t ws_size,
                              hipStream_t stream) {
  const float* X  = (const float*)d_in[0];
  const float* G  = (const float*)d_in[1];
  const float* GN = (const float*)d_in[2];
  float* out = (float*)d_out;

  char* ws = (char*)d_ws;
  unsigned short*     Gb2  = (unsigned short*)(ws + OFF_GB2);
  unsigned short*     Xs   = (unsigned short*)(ws + OFF_XS);
  unsigned long long* best = (unsigned long long*)(ws + OFF_B);

  e8_prep<<<(NCWP + NROWS + 255) / 256, 256, 0, stream>>>(X, G, GN, Gb2, Xs, best);
  e8_main<<<dim3(RB, NCHUNK), 256, 0, stream>>>(Gb2, Xs, best);
  e8_final<<<NROWS / 256, 256, 0, stream>>>(G, best, out);
}

// Round 7
// 61.709 us; speedup vs baseline: 1.3001x; 1.3001x over previous
//
#include <hip/hip_runtime.h>
#include <math.h>

// E8S codebook quantization via 32x32x16 bf16 MFMA pairs, exact 3-way split.
//   scores[r][c] = 2*X[r]·G[c] - ||G[c]||^2 ; idx = first-argmax over c.
// Exactness: G coords multiples of 0.25 (exact bf16); 2*X = h+m+l exact
// 3-term bf16 split; gn multiple of 0.5 < 16 (exact bf16).
// Tile = 32 codewords x 32 rows. K=16 = 2 dim-groups of 8 (kg = lane>>5):
//   MFMA1: A=coords(both kg), B=(kg? m : h)        -> (h+m)·g
//   MFMA2: A=(kg? [gn,0..]:coords), B=(kg? [-1,0..]:l), C=D1 -> +l·g - gn
// D layout (m74/m101): col=lane&31 (X row), cw_in_tile=(reg&3)+8*(reg>>2)+4*kg
// -> each lane holds 16 codeword scores of ONE row.
// Main pass tracks only (max score, tile id): 18 VALU / 1024 scores. Resolve
// pass re-runs the bit-identical MFMA chain on each row's winning tile and
// takes the smallest matching global index == np.argmax first-max semantics.

typedef short short8 __attribute__((ext_vector_type(8)));
typedef float f32x16 __attribute__((ext_vector_type(16)));

constexpr int NROWS  = 8192;
constexpr int NCW    = 55650;
constexpr int NT     = 1740;          // 32-codeword tiles
constexpr int NCWP   = NT * 32;       // 55680 (pads score ~ -3.4e38)
constexpr int NCHUNK = 64;            // tile chunks (grid.y)
constexpr int RBLK   = 32;            // row blocks of 256 rows (grid.x)

// workspace layout (bytes)
// Gb: [NCWP][16] ushort — 0..7 = bf16 coords, 8 = bf16 gn, 9..15 = 0
constexpr size_t OFF_GB = 0;
constexpr size_t OFF_XS = OFF_GB + (size_t)NCWP * 32;   // ushort Xs[NROWS*4*8]
constexpr size_t OFF_BK = OFF_XS + (size_t)NROWS * 64;  // u64 best[NROWS]
constexpr size_t OFF_BI = OFF_BK + (size_t)NROWS * 8;   // int  bidx[NROWS]

__device__ inline unsigned short bf16_rne(float f) {
  unsigned int u = __float_as_uint(f);
  unsigned int r = u + 0x7FFFu + ((u >> 16) & 1u);
  return (unsigned short)(r >> 16);
}
__device__ inline float bf16_f(unsigned short h) {
  return __uint_as_float(((unsigned int)h) << 16);
}
__device__ inline unsigned int enc_ord(float f) {  // monotonic float->uint
  unsigned int u = __float_as_uint(f);
  return (u & 0x80000000u) ? ~u : (u | 0x80000000u);
}
__device__ inline float dec_ord(unsigned int e) {
  unsigned int u = (e & 0x80000000u) ? (e & 0x7FFFFFFFu) : ~e;
  return __uint_as_float(u);
}

__global__ __launch_bounds__(256) void e8_prep(
    const float* __restrict__ X, const float* __restrict__ G,
    const float* __restrict__ GN, unsigned short* __restrict__ Gb,
    unsigned short* __restrict__ Xs, unsigned long long* __restrict__ best) {
  int i = blockIdx.x * 256 + threadIdx.x;
  if (i < NCWP) {
    unsigned short* g = Gb + (size_t)i * 16;
    if (i < NCW) {
      for (int j = 0; j < 8; ++j) g[j] = bf16_rne(G[(size_t)i*8+j]);
      g[8] = bf16_rne(GN[i]);           // exact: multiple of 0.5, < 16
      for (int j = 9; j < 16; ++j) g[j] = 0;
    } else {
      for (int j = 0; j < 8; ++j) g[j] = 0;
      g[8] = 0x7F7F;                    // bf16 max finite -> score ~ -3.4e38
      for (int j = 9; j < 16; ++j) g[j] = 0;
    }
  } else if (i < NCWP + NROWS) {
    int r = i - NCWP;
    for (int j = 0; j < 8; ++j) {
      float s = 2.0f * X[(size_t)r*8+j];           // exact
      unsigned short h = bf16_rne(s);  float r1 = s  - bf16_f(h);  // exact
      unsigned short m = bf16_rne(r1); float r2 = r1 - bf16_f(m);  // exact
      unsigned short l = bf16_rne(r2);             // residual after 3 terms = 0
      Xs[((size_t)r*4 + 0)*8 + j] = h;
      Xs[((size_t)r*4 + 1)*8 + j] = m;
      Xs[((size_t)r*4 + 2)*8 + j] = l;
      Xs[((size_t)r*4 + 3)*8 + j] = (j == 0) ? (unsigned short)0xBF80 : 0; // -1
    }
    best[r] = 0ull;   // below enc_ord of any real score
  }
}

// Per block: 4 waves x 2 row-tiles = 256 rows, chunk of ~27 cw-tiles.
__global__ __launch_bounds__(256, 4) void e8_main(
    const unsigned short* __restrict__ Gb,
    const unsigned short* __restrict__ Xs,
    unsigned long long* __restrict__ best) {
  const int lane = threadIdx.x & 63;
  const int wave = threadIdx.x >> 6;
  const int kg = lane >> 5, l31 = lane & 31;
  const int rowbase = blockIdx.x * 256 + wave * 64;

  short8 b1[2], b2[2];
#pragma unroll
  for (int t = 0; t < 2; ++t) {
    const size_t row = (size_t)rowbase + t*32 + l31;
    b1[t] = *reinterpret_cast<const short8*>(Xs + (row*4 + kg)*8);
    b2[t] = *reinterpret_cast<const short8*>(Xs + (row*4 + 2 + kg)*8);
  }

  const int ct0 = blockIdx.y * NT / NCHUNK;
  const int ct1 = (blockIdx.y + 1) * NT / NCHUNK;

  float bs[2] = {-INFINITY, -INFINITY};
  int   bi[2] = {0, 0};
  f32x16 cz;
#pragma unroll
  for (int i = 0; i < 16; ++i) cz[i] = 0.0f;

  for (int ct = ct0; ct < ct1; ++ct) {
    const unsigned short* ga = Gb + (size_t)ct * 512 + (size_t)l31 * 16;
    short8 a1 = *reinterpret_cast<const short8*>(ga);
    short8 a2 = *reinterpret_cast<const short8*>(ga + (kg << 3));
#pragma unroll
    for (int t = 0; t < 2; ++t) {
      f32x16 d = __builtin_amdgcn_mfma_f32_32x32x16_bf16(a1, b1[t], cz, 0, 0, 0);
      d = __builtin_amdgcn_mfma_f32_32x32x16_bf16(a2, b2[t], d, 0, 0, 0);
      float m = fmaxf(fmaxf(fmaxf(d[0], d[1]),  fmaxf(d[2], d[3])),
                      fmaxf(fmaxf(d[4], d[5]),  fmaxf(d[6], d[7])));
      m = fmaxf(m, fmaxf(fmaxf(fmaxf(d[8],  d[9]),  fmaxf(d[10], d[11])),
                         fmaxf(fmaxf(d[12], d[13]), fmaxf(d[14], d[15]))));
      bi[t] = (m > bs[t]) ? ct : bi[t];   // strict > -> earliest tile wins
      bs[t] = fmaxf(bs[t], m);
    }
  }

#pragma unroll
  for (int t = 0; t < 2; ++t) {
    unsigned long long key =
        ((unsigned long long)enc_ord(bs[t]) << 32) | (unsigned int)(~bi[t]);
    unsigned long long o = __shfl_xor(key, 32, 64);
    key = (o > key) ? o : key;          // merge the two kg half-sets of a row
    if (lane < 32)
      atomicMax(&best[(size_t)rowbase + t*32 + l31], key);
  }
}

// One wave per 32-row tile: re-run the bit-identical MFMA chain on each row's
// winning tile; smallest global index among score==rowmax.
__global__ __launch_bounds__(256) void e8_resolve(
    const unsigned short* __restrict__ Gb,
    const unsigned short* __restrict__ Xs,
    const unsigned long long* __restrict__ best, int* __restrict__ bidx) {
  const int lane = threadIdx.x & 63;
  const int wave = threadIdx.x >> 6;
  const int kg = lane >> 5, l31 = lane & 31;
  const int rt = blockIdx.x * 4 + wave;   // 0..255

  short8 b1, b2;
  {
    const size_t row = (size_t)rt * 32 + l31;
    b1 = *reinterpret_cast<const short8*>(Xs + (row*4 + kg)*8);
    b2 = *reinterpret_cast<const short8*>(Xs + (row*4 + 2 + kg)*8);
  }
  f32x16 cz;
#pragma unroll
  for (int i = 0; i < 16; ++i) cz[i] = 0.0f;

  for (int j = 0; j < 32; ++j) {
    const int srow = rt * 32 + j;
    const unsigned long long k = best[srow];
    const float sstar = dec_ord((unsigned int)(k >> 32));
    const int twin = (int)(~(unsigned int)(k & 0xFFFFFFFFull));

    const unsigned short* ga = Gb + (size_t)twin * 512 + (size_t)l31 * 16;
    short8 a1 = *reinterpret_cast<const short8*>(ga);
    short8 a2 = *reinterpret_cast<const short8*>(ga + (kg << 3));
    f32x16 d = __builtin_amdgcn_mfma_f32_32x32x16_bf16(a1, b1, cz, 0, 0, 0);
    d = __builtin_amdgcn_mfma_f32_32x32x16_bf16(a2, b2, d, 0, 0, 0);

    const int base = twin * 32 + 4 * kg;
    int cand = 0x7FFFFFFF;
#pragma unroll
    for (int r = 15; r >= 0; --r)       // descending -> smallest slot wins
      cand = (d[r] == sstar) ? (base + ((r & 3) + 8 * (r >> 2))) : cand;
    if (l31 != j) cand = 0x7FFFFFFF;    // only this row's two lanes count
    const int o = __shfl_xor(cand, 32, 64);
    cand = min(cand, o);
    if (lane == j) bidx[srow] = cand;
  }
}

__global__ __launch_bounds__(256) void e8_final(
    const float* __restrict__ G, const int* __restrict__ bidx,
    float* __restrict__ out) {
  const int r = blockIdx.x * 256 + threadIdx.x;
  const int idx = bidx[r];
  const float4* g = reinterpret_cast<const float4*>(G + (size_t)idx * 8);
  float4 v0 = g[0], v1 = g[1];
  float4* o = reinterpret_cast<float4*>(out + (size_t)r * 8);
  o[0] = v0; o[1] = v1;
  out[(size_t)NROWS * 8 + r] = (float)(idx - 32768);
}

extern "C" void kernel_launch(void* const* d_in, const int* in_sizes, int n_in,
                              void* d_out, int out_size, void* d_ws, size_t ws_size,
                              hipStream_t stream) {
  const float* X  = (const float*)d_in[0];
  const float* G  = (const float*)d_in[1];
  const float* GN = (const float*)d_in[2];
  float* out = (float*)d_out;

  char* ws = (char*)d_ws;
  unsigned short*     Gb   = (unsigned short*)(ws + OFF_GB);
  unsigned short*     Xs   = (unsigned short*)(ws + OFF_XS);
  unsigned long long* best = (unsigned long long*)(ws + OFF_BK);
  int*                bidx = (int*)(ws + OFF_BI);

  e8_prep<<<(NCWP + NROWS + 255) / 256, 256, 0, stream>>>(X, G, GN, Gb, Xs, best);
  e8_main<<<dim3(RBLK, NCHUNK), 256, 0, stream>>>(Gb, Xs, best);
  e8_resolve<<<64, 256, 0, stream>>>(Gb, Xs, best, bidx);
  e8_final<<<NROWS / 256, 256, 0, stream>>>(G, bidx, out);
}

// Round 8
// 48.716 us; speedup vs baseline: 1.6469x; 1.2667x over previous
//
#include <hip/hip_runtime.h>
#include <math.h>

// E8S codebook quantization via 32x32x16 bf16 MFMA pairs, exact 3-way split.
//   scores[r][c] = 2*X[r]·G[c] - ||G[c]||^2 ; idx = first-argmax over c.
// Exactness: G coords multiples of 0.25 (exact bf16); 2*X = h+m+l exact
// 3-term bf16 split; gn multiple of 0.5 < 16 (exact bf16).
// Tile = 32 codewords x 32 rows. K=16 = 2 dim-groups of 8 (kg = lane>>5):
//   MFMA1: A=coords(both kg), B=(kg? m : h)        -> (h+m)·g
//   MFMA2: A=(kg? [gn,0..]:coords), B=(kg? [-1,0..]:l), C=D1 -> +l·g - gn
// D layout (m74/m101): col=lane&31 (X row), cw_in_tile=(reg&3)+8*(reg>>2)+4*kg
// -> each lane holds 16 codeword scores of ONE row.
// R8: inline-asm MFMA with "v" constraints pins accumulators in ARCH VGPRs —
// R7's counters (VGPR_Count=32, ~100 VALU/iter vs 44 in source) showed the
// compiler put D in AGPRs and paid 16 accvgpr_write + 16 accvgpr_read per
// t-unit. Main pass tracks only (max score, tile id); resolve re-runs the
// bit-identical chain on each row's winning tile (np.argmax first-max).

typedef short short8 __attribute__((ext_vector_type(8)));
typedef float f32x16 __attribute__((ext_vector_type(16)));

constexpr int NROWS  = 8192;
constexpr int NCW    = 55650;
constexpr int NT     = 1740;          // 32-codeword tiles
constexpr int NCWP   = NT * 32;       // 55680 (pads score ~ -3.4e38)
constexpr int NCHUNK = 64;            // tile chunks (grid.y)
constexpr int RBLK   = 32;            // row blocks of 256 rows (grid.x)

// workspace layout (bytes)
// Gb: [NCWP][16] ushort — 0..7 = bf16 coords, 8 = bf16 gn, 9..15 = 0
constexpr size_t OFF_GB = 0;
constexpr size_t OFF_XS = OFF_GB + (size_t)NCWP * 32;   // ushort Xs[NROWS*4*8]
constexpr size_t OFF_BK = OFF_XS + (size_t)NROWS * 64;  // u64 best[NROWS]
constexpr size_t OFF_BI = OFF_BK + (size_t)NROWS * 8;   // int  bidx[NROWS]

__device__ inline unsigned short bf16_rne(float f) {
  unsigned int u = __float_as_uint(f);
  unsigned int r = u + 0x7FFFu + ((u >> 16) & 1u);
  return (unsigned short)(r >> 16);
}
__device__ inline float bf16_f(unsigned short h) {
  return __uint_as_float(((unsigned int)h) << 16);
}
__device__ inline unsigned int enc_ord(float f) {  // monotonic float->uint
  unsigned int u = __float_as_uint(f);
  return (u & 0x80000000u) ? ~u : (u | 0x80000000u);
}
__device__ inline float dec_ord(unsigned int e) {
  unsigned int u = (e & 0x80000000u) ? (e & 0x7FFFFFFFu) : ~e;
  return __uint_as_float(u);
}
__device__ inline float max16(const f32x16& d) {   // max3-shaped tree (8 ops)
  float t1 = fmaxf(fmaxf(d[0], d[1]), d[2]);
  float t2 = fmaxf(fmaxf(d[3], d[4]), d[5]);
  float t3 = fmaxf(fmaxf(d[6], d[7]), d[8]);
  float t4 = fmaxf(fmaxf(d[9], d[10]), d[11]);
  float t5 = fmaxf(fmaxf(d[12], d[13]), d[14]);
  float u1 = fmaxf(fmaxf(t1, t2), t3);
  float u2 = fmaxf(fmaxf(t4, t5), d[15]);
  return fmaxf(u1, u2);
}

__global__ __launch_bounds__(256) void e8_prep(
    const float* __restrict__ X, const float* __restrict__ G,
    const float* __restrict__ GN, unsigned short* __restrict__ Gb,
    unsigned short* __restrict__ Xs, unsigned long long* __restrict__ best) {
  int i = blockIdx.x * 256 + threadIdx.x;
  if (i < NCWP) {
    unsigned short g16[16];
    if (i < NCW) {
      for (int j = 0; j < 8; ++j) g16[j] = bf16_rne(G[(size_t)i*8+j]);
      g16[8] = bf16_rne(GN[i]);         // exact: multiple of 0.5, < 16
      for (int j = 9; j < 16; ++j) g16[j] = 0;
    } else {
      for (int j = 0; j < 8; ++j) g16[j] = 0;
      g16[8] = 0x7F7F;                  // bf16 max finite -> score ~ -3.4e38
      for (int j = 9; j < 16; ++j) g16[j] = 0;
    }
    uint4* dst = reinterpret_cast<uint4*>(Gb + (size_t)i * 16);
    dst[0] = *reinterpret_cast<uint4*>(&g16[0]);
    dst[1] = *reinterpret_cast<uint4*>(&g16[8]);
  } else if (i < NCWP + NROWS) {
    int r = i - NCWP;
    unsigned short hh[8], mm[8], ll[8], qq[8];
    for (int j = 0; j < 8; ++j) {
      float s = 2.0f * X[(size_t)r*8+j];           // exact
      unsigned short h = bf16_rne(s);  float r1 = s  - bf16_f(h);  // exact
      unsigned short m = bf16_rne(r1); float r2 = r1 - bf16_f(m);  // exact
      unsigned short l = bf16_rne(r2);             // residual after 3 terms = 0
      hh[j] = h; mm[j] = m; ll[j] = l;
      qq[j] = (j == 0) ? (unsigned short)0xBF80 : 0;  // -1.0
    }
    uint4* dst = reinterpret_cast<uint4*>(Xs + (size_t)r * 32);
    dst[0] = *reinterpret_cast<uint4*>(hh);
    dst[1] = *reinterpret_cast<uint4*>(mm);
    dst[2] = *reinterpret_cast<uint4*>(ll);
    dst[3] = *reinterpret_cast<uint4*>(qq);
    best[r] = 0ull;   // below enc_ord of any real score
  }
}

// Per block: 4 waves x 2 row-tiles = 256 rows, chunk of ~27 cw-tiles.
__global__ __launch_bounds__(256, 4) void e8_main(
    const unsigned short* __restrict__ Gb,
    const unsigned short* __restrict__ Xs,
    unsigned long long* __restrict__ best) {
  const int lane = threadIdx.x & 63;
  const int wave = threadIdx.x >> 6;
  const int kg = lane >> 5, l31 = lane & 31;
  const int rowbase = blockIdx.x * 256 + wave * 64;

  short8 b10, b11, b20, b21;
  {
    const size_t row0 = (size_t)rowbase + l31;
    const size_t row1 = row0 + 32;
    b10 = *reinterpret_cast<const short8*>(Xs + (row0*4 + kg)*8);
    b20 = *reinterpret_cast<const short8*>(Xs + (row0*4 + 2 + kg)*8);
    b11 = *reinterpret_cast<const short8*>(Xs + (row1*4 + kg)*8);
    b21 = *reinterpret_cast<const short8*>(Xs + (row1*4 + 2 + kg)*8);
  }

  const int ct0 = blockIdx.y * NT / NCHUNK;
  const int ct1 = (blockIdx.y + 1) * NT / NCHUNK;

  f32x16 cz;
#pragma unroll
  for (int i = 0; i < 16; ++i) cz[i] = 0.0f;

  float bs0 = -INFINITY, bs1 = -INFINITY;
  int   bi0 = 0,         bi1 = 0;

  const unsigned short* p = Gb + (size_t)ct0 * 512 + (size_t)l31 * 16;
  const int koff = kg << 3;   // a2 slice: coords (kg=0) or [gn,0..] (kg=1)

  for (int ct = ct0; ct < ct1; ++ct) {
    short8 a1 = *reinterpret_cast<const short8*>(p);
    short8 a2 = *reinterpret_cast<const short8*>(p + koff);
    p += 512;

    f32x16 d0, d1;
    asm volatile(
        "v_mfma_f32_32x32x16_bf16 %0, %2, %4, %8\n\t"
        "v_mfma_f32_32x32x16_bf16 %1, %2, %5, %8\n\t"
        "v_mfma_f32_32x32x16_bf16 %0, %3, %6, %0\n\t"
        "v_mfma_f32_32x32x16_bf16 %1, %3, %7, %1\n\t"
        "s_nop 7\n\t"
        "s_nop 7"
        : "=&v"(d0), "=&v"(d1)
        : "v"(a1), "v"(a2), "v"(b10), "v"(b11), "v"(b20), "v"(b21), "v"(cz));

    const float m0 = max16(d0);
    const float m1 = max16(d1);
    bi0 = (m0 > bs0) ? ct : bi0;   // strict > -> earliest tile wins
    bs0 = fmaxf(bs0, m0);
    bi1 = (m1 > bs1) ? ct : bi1;
    bs1 = fmaxf(bs1, m1);
  }

  {
    unsigned long long key =
        ((unsigned long long)enc_ord(bs0) << 32) | (unsigned int)(~bi0);
    unsigned long long o = __shfl_xor(key, 32, 64);
    key = (o > key) ? o : key;          // merge the two kg half-sets of a row
    if (lane < 32) atomicMax(&best[(size_t)rowbase + l31], key);
  }
  {
    unsigned long long key =
        ((unsigned long long)enc_ord(bs1) << 32) | (unsigned int)(~bi1);
    unsigned long long o = __shfl_xor(key, 32, 64);
    key = (o > key) ? o : key;
    if (lane < 32) atomicMax(&best[(size_t)rowbase + 32 + l31], key);
  }
}

// 256 blocks x 4 waves; wave handles 8 rows of its 32-row tile: re-run the
// bit-identical MFMA chain on each row's winning tile; smallest matching idx.
__global__ __launch_bounds__(256) void e8_resolve(
    const unsigned short* __restrict__ Gb,
    const unsigned short* __restrict__ Xs,
    const unsigned long long* __restrict__ best, int* __restrict__ bidx) {
  const int lane = threadIdx.x & 63;
  const int wave = threadIdx.x >> 6;
  const int kg = lane >> 5, l31 = lane & 31;
  const int rt = blockIdx.x;              // 0..255

  short8 b1, b2;
  {
    const size_t row = (size_t)rt * 32 + l31;
    b1 = *reinterpret_cast<const short8*>(Xs + (row*4 + kg)*8);
    b2 = *reinterpret_cast<const short8*>(Xs + (row*4 + 2 + kg)*8);
  }
  f32x16 cz;
#pragma unroll
  for (int i = 0; i < 16; ++i) cz[i] = 0.0f;

  for (int j = wave * 8; j < wave * 8 + 8; ++j) {
    const int srow = rt * 32 + j;
    const unsigned long long k = best[srow];
    const float sstar = dec_ord((unsigned int)(k >> 32));
    const int twin = (int)(~(unsigned int)(k & 0xFFFFFFFFull));

    const unsigned short* ga = Gb + (size_t)twin * 512 + (size_t)l31 * 16;
    short8 a1 = *reinterpret_cast<const short8*>(ga);
    short8 a2 = *reinterpret_cast<const short8*>(ga + (kg << 3));
    f32x16 d = __builtin_amdgcn_mfma_f32_32x32x16_bf16(a1, b1, cz, 0, 0, 0);
    d = __builtin_amdgcn_mfma_f32_32x32x16_bf16(a2, b2, d, 0, 0, 0);

    const int base = twin * 32 + 4 * kg;
    int cand = 0x7FFFFFFF;
#pragma unroll
    for (int r = 15; r >= 0; --r)       // descending -> smallest slot wins
      cand = (d[r] == sstar) ? (base + ((r & 3) + 8 * (r >> 2))) : cand;
    if (l31 != j) cand = 0x7FFFFFFF;    // only this row's two lanes count
    const int o = __shfl_xor(cand, 32, 64);
    cand = min(cand, o);
    if (lane == j) bidx[srow] = cand;
  }
}

__global__ __launch_bounds__(256) void e8_final(
    const float* __restrict__ G, const int* __restrict__ bidx,
    float* __restrict__ out) {
  const int r = blockIdx.x * 256 + threadIdx.x;
  const int idx = bidx[r];
  const float4* g = reinterpret_cast<const float4*>(G + (size_t)idx * 8);
  float4 v0 = g[0], v1 = g[1];
  float4* o = reinterpret_cast<float4*>(out + (size_t)r * 8);
  o[0] = v0; o[1] = v1;
  out[(size_t)NROWS * 8 + r] = (float)(idx - 32768);
}

extern "C" void kernel_launch(void* const* d_in, const int* in_sizes, int n_in,
                              void* d_out, int out_size, void* d_ws, size_t ws_size,
                              hipStream_t stream) {
  const float* X  = (const float*)d_in[0];
  const float* G  = (const float*)d_in[1];
  const float* GN = (const float*)d_in[2];
  float* out = (float*)d_out;

  char* ws = (char*)d_ws;
  unsigned short*     Gb   = (unsigned short*)(ws + OFF_GB);
  unsigned short*     Xs   = (unsigned short*)(ws + OFF_XS);
  unsigned long long* best = (unsigned long long*)(ws + OFF_BK);
  int*                bidx = (int*)(ws + OFF_BI);

  e8_prep<<<(NCWP + NROWS + 255) / 256, 256, 0, stream>>>(X, G, GN, Gb, Xs, best);
  e8_main<<<dim3(RBLK, NCHUNK), 256, 0, stream>>>(Gb, Xs, best);
  e8_resolve<<<256, 256, 0, stream>>>(Gb, Xs, best, bidx);
  e8_final<<<NROWS / 256, 256, 0, stream>>>(G, bidx, out);
}

// Round 9
// 46.013 us; speedup vs baseline: 1.7436x; 1.0587x over previous
//
#include <hip/hip_runtime.h>
#include <math.h>

// E8S codebook quantization via 32x32x16 bf16 MFMA pairs, exact 3-way split.
//   scores[r][c] = 2*X[r]·G[c] - ||G[c]||^2 ; idx = first-argmax over c.
// Exactness: G coords multiples of 0.25 (exact bf16); 2*X = h+m+l exact
// 3-term bf16 split; gn multiple of 0.5 < 16 (exact bf16).
// Tile = 32 codewords x 32 rows. K=16 = 2 dim-groups of 8 (kg = lane>>5):
//   MFMA1: A=coords(both kg), B=(kg? m : h)        -> (h+m)·g
//   MFMA2: A=(kg? [gn,0..]:coords), B=(kg? [-1,0..]:l), C=D1 -> +l·g - gn
// D layout (m74/m101): col=lane&31 (X row), cw_in_tile=(reg&3)+8*(reg>>2)+4*kg
// -> each lane holds 16 codeword scores of ONE row.
// R8: inline-asm MFMA pins accumulators in arch VGPRs (no accvgpr churn).
// R9: 1-deep register prefetch of next G tile (breaks per-iter load->MFMA
// serialization), NCHUNK 32 (4 waves/SIMD exactly, half the atomics),
// resolve+final fused. Resolve re-runs the bit-identical chain on each row's
// winning tile -> smallest matching index == np.argmax first-max.

typedef short short8 __attribute__((ext_vector_type(8)));
typedef float f32x16 __attribute__((ext_vector_type(16)));

constexpr int NROWS  = 8192;
constexpr int NCW    = 55650;
constexpr int NT     = 1740;          // 32-codeword tiles
constexpr int NCWP   = NT * 32;       // 55680 (pads score ~ -3.4e38)
constexpr int NCHUNK = 32;            // tile chunks (grid.y)
constexpr int RBLK   = 32;            // row blocks of 256 rows (grid.x)

// workspace layout (bytes)
// Gb: [NCWP][16] ushort — 0..7 = bf16 coords, 8 = bf16 gn, 9..15 = 0
constexpr size_t OFF_GB = 0;
constexpr size_t OFF_XS = OFF_GB + (size_t)NCWP * 32;   // ushort Xs[NROWS*4*8]
constexpr size_t OFF_BK = OFF_XS + (size_t)NROWS * 64;  // u64 best[NROWS]

__device__ inline unsigned short bf16_rne(float f) {
  unsigned int u = __float_as_uint(f);
  unsigned int r = u + 0x7FFFu + ((u >> 16) & 1u);
  return (unsigned short)(r >> 16);
}
__device__ inline float bf16_f(unsigned short h) {
  return __uint_as_float(((unsigned int)h) << 16);
}
__device__ inline unsigned int enc_ord(float f) {  // monotonic float->uint
  unsigned int u = __float_as_uint(f);
  return (u & 0x80000000u) ? ~u : (u | 0x80000000u);
}
__device__ inline float dec_ord(unsigned int e) {
  unsigned int u = (e & 0x80000000u) ? (e & 0x7FFFFFFFu) : ~e;
  return __uint_as_float(u);
}
__device__ inline float max16(const f32x16& d) {   // max3-shaped tree (8 ops)
  float t1 = fmaxf(fmaxf(d[0], d[1]), d[2]);
  float t2 = fmaxf(fmaxf(d[3], d[4]), d[5]);
  float t3 = fmaxf(fmaxf(d[6], d[7]), d[8]);
  float t4 = fmaxf(fmaxf(d[9], d[10]), d[11]);
  float t5 = fmaxf(fmaxf(d[12], d[13]), d[14]);
  float u1 = fmaxf(fmaxf(t1, t2), t3);
  float u2 = fmaxf(fmaxf(t4, t5), d[15]);
  return fmaxf(u1, u2);
}

__global__ __launch_bounds__(256) void e8_prep(
    const float* __restrict__ X, const float* __restrict__ G,
    const float* __restrict__ GN, unsigned short* __restrict__ Gb,
    unsigned short* __restrict__ Xs, unsigned long long* __restrict__ best) {
  int i = blockIdx.x * 256 + threadIdx.x;
  if (i < NCWP) {
    unsigned short g16[16];
    if (i < NCW) {
      for (int j = 0; j < 8; ++j) g16[j] = bf16_rne(G[(size_t)i*8+j]);
      g16[8] = bf16_rne(GN[i]);         // exact: multiple of 0.5, < 16
      for (int j = 9; j < 16; ++j) g16[j] = 0;
    } else {
      for (int j = 0; j < 8; ++j) g16[j] = 0;
      g16[8] = 0x7F7F;                  // bf16 max finite -> score ~ -3.4e38
      for (int j = 9; j < 16; ++j) g16[j] = 0;
    }
    uint4* dst = reinterpret_cast<uint4*>(Gb + (size_t)i * 16);
    dst[0] = *reinterpret_cast<uint4*>(&g16[0]);
    dst[1] = *reinterpret_cast<uint4*>(&g16[8]);
  } else if (i < NCWP + NROWS) {
    int r = i - NCWP;
    unsigned short hh[8], mm[8], ll[8], qq[8];
    for (int j = 0; j < 8; ++j) {
      float s = 2.0f * X[(size_t)r*8+j];           // exact
      unsigned short h = bf16_rne(s);  float r1 = s  - bf16_f(h);  // exact
      unsigned short m = bf16_rne(r1); float r2 = r1 - bf16_f(m);  // exact
      unsigned short l = bf16_rne(r2);             // residual after 3 terms = 0
      hh[j] = h; mm[j] = m; ll[j] = l;
      qq[j] = (j == 0) ? (unsigned short)0xBF80 : 0;  // -1.0
    }
    uint4* dst = reinterpret_cast<uint4*>(Xs + (size_t)r * 32);
    dst[0] = *reinterpret_cast<uint4*>(hh);
    dst[1] = *reinterpret_cast<uint4*>(mm);
    dst[2] = *reinterpret_cast<uint4*>(ll);
    dst[3] = *reinterpret_cast<uint4*>(qq);
    best[r] = 0ull;   // below enc_ord of any real score
  }
}

// Per block: 4 waves x 2 row-tiles = 256 rows, chunk of ~54 cw-tiles.
// Grid 32x32 = 1024 blocks = 4 blocks/CU = 4 waves/SIMD, one pass.
__global__ __launch_bounds__(256, 4) void e8_main(
    const unsigned short* __restrict__ Gb,
    const unsigned short* __restrict__ Xs,
    unsigned long long* __restrict__ best) {
  const int lane = threadIdx.x & 63;
  const int wave = threadIdx.x >> 6;
  const int kg = lane >> 5, l31 = lane & 31;
  const int rowbase = blockIdx.x * 256 + wave * 64;

  short8 b10, b11, b20, b21;
  {
    const size_t row0 = (size_t)rowbase + l31;
    const size_t row1 = row0 + 32;
    b10 = *reinterpret_cast<const short8*>(Xs + (row0*4 + kg)*8);
    b20 = *reinterpret_cast<const short8*>(Xs + (row0*4 + 2 + kg)*8);
    b11 = *reinterpret_cast<const short8*>(Xs + (row1*4 + kg)*8);
    b21 = *reinterpret_cast<const short8*>(Xs + (row1*4 + 2 + kg)*8);
  }
  asm("" : "+v"(b10), "+v"(b11), "+v"(b20), "+v"(b21));  // keep resident

  const int ct0 = blockIdx.y * NT / NCHUNK;
  const int ct1 = (blockIdx.y + 1) * NT / NCHUNK;

  f32x16 cz;
#pragma unroll
  for (int i = 0; i < 16; ++i) cz[i] = 0.0f;

  float bs0 = -INFINITY, bs1 = -INFINITY;
  int   bi0 = 0,         bi1 = 0;

  const unsigned short* p = Gb + (size_t)ct0 * 512 + (size_t)l31 * 16;
  const int koff = kg << 3;   // a2 slice: coords (kg=0) or [gn,0..] (kg=1)

  // 1-deep software pipeline: next tile's fragments load while current tile
  // computes. (Prefetch past the last tile reads the Xs region — harmless,
  // values never consumed.)
  short8 a1 = *reinterpret_cast<const short8*>(p);
  short8 a2 = *reinterpret_cast<const short8*>(p + koff);

  for (int ct = ct0; ct < ct1; ++ct) {
    p += 512;
    short8 na1 = *reinterpret_cast<const short8*>(p);
    short8 na2 = *reinterpret_cast<const short8*>(p + koff);

    f32x16 d0, d1;
    asm volatile(
        "v_mfma_f32_32x32x16_bf16 %0, %2, %4, %8\n\t"
        "v_mfma_f32_32x32x16_bf16 %1, %2, %5, %8\n\t"
        "v_mfma_f32_32x32x16_bf16 %0, %3, %6, %0\n\t"
        "v_mfma_f32_32x32x16_bf16 %1, %3, %7, %1\n\t"
        "s_nop 7\n\t"
        "s_nop 7"
        : "=&v"(d0), "=&v"(d1)
        : "v"(a1), "v"(a2), "v"(b10), "v"(b11), "v"(b20), "v"(b21), "v"(cz));

    const float m0 = max16(d0);
    const float m1 = max16(d1);
    bi0 = (m0 > bs0) ? ct : bi0;   // strict > -> earliest tile wins
    bs0 = fmaxf(bs0, m0);
    bi1 = (m1 > bs1) ? ct : bi1;
    bs1 = fmaxf(bs1, m1);
    a1 = na1; a2 = na2;
  }

  {
    unsigned long long key =
        ((unsigned long long)enc_ord(bs0) << 32) | (unsigned int)(~bi0);
    unsigned long long o = __shfl_xor(key, 32, 64);
    key = (o > key) ? o : key;          // merge the two kg half-sets of a row
    if (lane < 32) atomicMax(&best[(size_t)rowbase + l31], key);
  }
  {
    unsigned long long key =
        ((unsigned long long)enc_ord(bs1) << 32) | (unsigned int)(~bi1);
    unsigned long long o = __shfl_xor(key, 32, 64);
    key = (o > key) ? o : key;
    if (lane < 32) atomicMax(&best[(size_t)rowbase + 32 + l31], key);
  }
}

// 256 blocks x 4 waves; wave handles 8 rows of its 32-row tile: re-run the
// bit-identical MFMA chain on each row's winning tile, find smallest matching
// index, and write the output row (vals + idx) directly.
__global__ __launch_bounds__(256) void e8_resolve(
    const unsigned short* __restrict__ Gb,
    const unsigned short* __restrict__ Xs, const float* __restrict__ G,
    const unsigned long long* __restrict__ best, float* __restrict__ out) {
  const int lane = threadIdx.x & 63;
  const int wave = threadIdx.x >> 6;
  const int kg = lane >> 5, l31 = lane & 31;
  const int rt = blockIdx.x;              // 0..255

  short8 b1, b2;
  {
    const size_t row = (size_t)rt * 32 + l31;
    b1 = *reinterpret_cast<const short8*>(Xs + (row*4 + kg)*8);
    b2 = *reinterpret_cast<const short8*>(Xs + (row*4 + 2 + kg)*8);
  }
  f32x16 cz;
#pragma unroll
  for (int i = 0; i < 16; ++i) cz[i] = 0.0f;

  for (int j = wave * 8; j < wave * 8 + 8; ++j) {
    const int srow = rt * 32 + j;
    const unsigned long long k = best[srow];
    const float sstar = dec_ord((unsigned int)(k >> 32));
    const int twin = (int)(~(unsigned int)(k & 0xFFFFFFFFull));

    const unsigned short* ga = Gb + (size_t)twin * 512 + (size_t)l31 * 16;
    short8 a1 = *reinterpret_cast<const short8*>(ga);
    short8 a2 = *reinterpret_cast<const short8*>(ga + (kg << 3));
    f32x16 d = __builtin_amdgcn_mfma_f32_32x32x16_bf16(a1, b1, cz, 0, 0, 0);
    d = __builtin_amdgcn_mfma_f32_32x32x16_bf16(a2, b2, d, 0, 0, 0);

    const int base = twin * 32 + 4 * kg;
    int cand = 0x7FFFFFFF;
#pragma unroll
    for (int r = 15; r >= 0; --r)       // descending -> smallest slot wins
      cand = (d[r] == sstar) ? (base + ((r & 3) + 8 * (r >> 2))) : cand;
    if (l31 != j) cand = 0x7FFFFFFF;    // only this row's two lanes count
    const int o = __shfl_xor(cand, 32, 64);
    cand = min(cand, o);
    if (lane == j) {                    // kg=0 owner lane writes the row
      const float4* g = reinterpret_cast<const float4*>(G + (size_t)cand * 8);
      float4 v0 = g[0], v1 = g[1];
      float4* od = reinterpret_cast<float4*>(out + (size_t)srow * 8);
      od[0] = v0; od[1] = v1;
      out[(size_t)NROWS * 8 + srow] = (float)(cand - 32768);
    }
  }
}

extern "C" void kernel_launch(void* const* d_in, const int* in_sizes, int n_in,
                              void* d_out, int out_size, void* d_ws, size_t ws_size,
                              hipStream_t stream) {
  const float* X  = (const float*)d_in[0];
  const float* G  = (const float*)d_in[1];
  const float* GN = (const float*)d_in[2];
  float* out = (float*)d_out;

  char* ws = (char*)d_ws;
  unsigned short*     Gb   = (unsigned short*)(ws + OFF_GB);
  unsigned short*     Xs   = (unsigned short*)(ws + OFF_XS);
  unsigned long long* best = (unsigned long long*)(ws + OFF_BK);

  e8_prep<<<(NCWP + NROWS + 255) / 256, 256, 0, stream>>>(X, G, GN, Gb, Xs, best);
  e8_main<<<dim3(RBLK, NCHUNK), 256, 0, stream>>>(Gb, Xs, best);
  e8_resolve<<<256, 256, 0, stream>>>(Gb, Xs, G, best, out);
}

// Round 10
// 43.564 us; speedup vs baseline: 1.8417x; 1.0562x over previous
//
#include <hip/hip_runtime.h>
#include <math.h>

// E8S codebook quantization via 32x32x16 bf16 MFMA pairs, exact 3-way split.
//   scores[r][c] = 2*X[r]·G[c] - ||G[c]||^2 ; idx = first-argmax over c.
// Exactness: G coords multiples of 0.25 (exact bf16); 2*X = h+m+l exact
// 3-term bf16 split; gn multiple of 0.5 < 16 (exact bf16).
// Tile = 32 codewords x 32 rows. K=16 = 2 dim-groups of 8 (kg = lane>>5):
//   stage1: A=coords(both kg), B=(kg? m : h)        -> (h+m)·g
//   stage2: A=(kg? [gn,0..]:coords), B=(kg? [-1,0..]:l), C=stage1 -> +l·g - gn
// D layout (m74/m101): col=lane&31 (X row), cw_in_tile=(reg&3)+8*(reg>>2)+4*kg
// -> each lane holds 16 codeword scores of ONE row.
// R8: inline-asm MFMA pins accumulators in arch VGPRs (no accvgpr churn).
// R10: 4 row-tiles per wave (8 MFMA per 2 G-loads -> 2x arithmetic intensity)
// + 2-deep a-frag prefetch (~500cyc latency cover) + 3 blocks/CU VGPR budget.
// Main pass tracks only (max score, tile id); resolve re-runs the
// bit-identical chain on each row's winning tile (np.argmax first-max).

typedef short short8 __attribute__((ext_vector_type(8)));
typedef float f32x16 __attribute__((ext_vector_type(16)));

constexpr int NROWS  = 8192;
constexpr int NCW    = 55650;
constexpr int NT     = 1740;          // 32-codeword tiles
constexpr int NCWP   = NT * 32;       // 55680 (pads score ~ -3.4e38)
constexpr int NCHUNK = 48;            // tile chunks (grid.y)
constexpr int RBLK   = 16;            // row blocks of 512 rows (grid.x)

// workspace layout (bytes)
// Gb: [NCWP][16] ushort — 0..7 = bf16 coords, 8 = bf16 gn, 9..15 = 0
constexpr size_t OFF_GB = 0;
constexpr size_t OFF_XS = OFF_GB + (size_t)NCWP * 32;   // ushort Xs[NROWS*4*8]
constexpr size_t OFF_BK = OFF_XS + (size_t)NROWS * 64;  // u64 best[NROWS]

__device__ inline unsigned short bf16_rne(float f) {
  unsigned int u = __float_as_uint(f);
  unsigned int r = u + 0x7FFFu + ((u >> 16) & 1u);
  return (unsigned short)(r >> 16);
}
__device__ inline float bf16_f(unsigned short h) {
  return __uint_as_float(((unsigned int)h) << 16);
}
__device__ inline unsigned int enc_ord(float f) {  // monotonic float->uint
  unsigned int u = __float_as_uint(f);
  return (u & 0x80000000u) ? ~u : (u | 0x80000000u);
}
__device__ inline float dec_ord(unsigned int e) {
  unsigned int u = (e & 0x80000000u) ? (e & 0x7FFFFFFFu) : ~e;
  return __uint_as_float(u);
}
__device__ inline float max16(const f32x16& d) {   // max3-shaped tree (8 ops)
  float t1 = fmaxf(fmaxf(d[0], d[1]), d[2]);
  float t2 = fmaxf(fmaxf(d[3], d[4]), d[5]);
  float t3 = fmaxf(fmaxf(d[6], d[7]), d[8]);
  float t4 = fmaxf(fmaxf(d[9], d[10]), d[11]);
  float t5 = fmaxf(fmaxf(d[12], d[13]), d[14]);
  float u1 = fmaxf(fmaxf(t1, t2), t3);
  float u2 = fmaxf(fmaxf(t4, t5), d[15]);
  return fmaxf(u1, u2);
}

__global__ __launch_bounds__(256) void e8_prep(
    const float* __restrict__ X, const float* __restrict__ G,
    const float* __restrict__ GN, unsigned short* __restrict__ Gb,
    unsigned short* __restrict__ Xs, unsigned long long* __restrict__ best) {
  int i = blockIdx.x * 256 + threadIdx.x;
  if (i < NCWP) {
    unsigned short g16[16];
    if (i < NCW) {
      for (int j = 0; j < 8; ++j) g16[j] = bf16_rne(G[(size_t)i*8+j]);
      g16[8] = bf16_rne(GN[i]);         // exact: multiple of 0.5, < 16
      for (int j = 9; j < 16; ++j) g16[j] = 0;
    } else {
      for (int j = 0; j < 8; ++j) g16[j] = 0;
      g16[8] = 0x7F7F;                  // bf16 max finite -> score ~ -3.4e38
      for (int j = 9; j < 16; ++j) g16[j] = 0;
    }
    uint4* dst = reinterpret_cast<uint4*>(Gb + (size_t)i * 16);
    dst[0] = *reinterpret_cast<uint4*>(&g16[0]);
    dst[1] = *reinterpret_cast<uint4*>(&g16[8]);
  } else if (i < NCWP + NROWS) {
    int r = i - NCWP;
    unsigned short hh[8], mm[8], ll[8], qq[8];
    for (int j = 0; j < 8; ++j) {
      float s = 2.0f * X[(size_t)r*8+j];           // exact
      unsigned short h = bf16_rne(s);  float r1 = s  - bf16_f(h);  // exact
      unsigned short m = bf16_rne(r1); float r2 = r1 - bf16_f(m);  // exact
      unsigned short l = bf16_rne(r2);             // residual after 3 terms = 0
      hh[j] = h; mm[j] = m; ll[j] = l;
      qq[j] = (j == 0) ? (unsigned short)0xBF80 : 0;  // -1.0
    }
    uint4* dst = reinterpret_cast<uint4*>(Xs + (size_t)r * 32);
    dst[0] = *reinterpret_cast<uint4*>(hh);
    dst[1] = *reinterpret_cast<uint4*>(mm);
    dst[2] = *reinterpret_cast<uint4*>(ll);
    dst[3] = *reinterpret_cast<uint4*>(qq);
    best[r] = 0ull;   // below enc_ord of any real score
  }
}

// Per block: 4 waves x 4 row-tiles = 512 rows, chunk of ~36 cw-tiles.
// Grid 16x48 = 768 blocks = 3 blocks/CU = 3 waves/SIMD (VGPR cap ~170).
__global__ __launch_bounds__(256, 3) void e8_main(
    const unsigned short* __restrict__ Gb,
    const unsigned short* __restrict__ Xs,
    unsigned long long* __restrict__ best) {
  const int lane = threadIdx.x & 63;
  const int wave = threadIdx.x >> 6;
  const int kg = lane >> 5, l31 = lane & 31;
  const int rowbase = blockIdx.x * 512 + wave * 128;

  short8 b1f[4], b2f[4];
#pragma unroll
  for (int t = 0; t < 4; ++t) {
    const size_t row = (size_t)rowbase + t * 32 + l31;
    b1f[t] = *reinterpret_cast<const short8*>(Xs + (row*4 + kg)*8);
    b2f[t] = *reinterpret_cast<const short8*>(Xs + (row*4 + 2 + kg)*8);
  }
  asm("" : "+v"(b1f[0]), "+v"(b1f[1]), "+v"(b1f[2]), "+v"(b1f[3]),
           "+v"(b2f[0]), "+v"(b2f[1]), "+v"(b2f[2]), "+v"(b2f[3]));

  const int ct0 = blockIdx.y * NT / NCHUNK;
  const int ct1 = (blockIdx.y + 1) * NT / NCHUNK;

  f32x16 cz;
#pragma unroll
  for (int i = 0; i < 16; ++i) cz[i] = 0.0f;

  float bs[4] = {-INFINITY, -INFINITY, -INFINITY, -INFINITY};
  int   bi[4] = {0, 0, 0, 0};

  const unsigned short* p = Gb + (size_t)ct0 * 512 + (size_t)l31 * 16;
  const int koff = kg << 3;   // a2 slice: coords (kg=0) or [gn,0..] (kg=1)

  // 2-deep software pipeline: a-frags for ct+1 and ct+2 in flight while ct
  // computes. (Overrun past the last tile reads the Xs region — harmless.)
  short8 a1_0 = *reinterpret_cast<const short8*>(p);
  short8 a2_0 = *reinterpret_cast<const short8*>(p + koff);
  p += 512;
  short8 a1_1 = *reinterpret_cast<const short8*>(p);
  short8 a2_1 = *reinterpret_cast<const short8*>(p + koff);

  for (int ct = ct0; ct < ct1; ++ct) {
    p += 512;
    short8 na1 = *reinterpret_cast<const short8*>(p);
    short8 na2 = *reinterpret_cast<const short8*>(p + koff);

    f32x16 d0, d1, d2, d3;
    asm volatile(
        "v_mfma_f32_32x32x16_bf16 %0, %4, %6, %14\n\t"
        "v_mfma_f32_32x32x16_bf16 %1, %4, %7, %14\n\t"
        "v_mfma_f32_32x32x16_bf16 %2, %4, %8, %14\n\t"
        "v_mfma_f32_32x32x16_bf16 %3, %4, %9, %14\n\t"
        "v_mfma_f32_32x32x16_bf16 %0, %5, %10, %0\n\t"
        "v_mfma_f32_32x32x16_bf16 %1, %5, %11, %1\n\t"
        "v_mfma_f32_32x32x16_bf16 %2, %5, %12, %2\n\t"
        "v_mfma_f32_32x32x16_bf16 %3, %5, %13, %3\n\t"
        "s_nop 7\n\t"
        "s_nop 7"
        : "=&v"(d0), "=&v"(d1), "=&v"(d2), "=&v"(d3)
        : "v"(a1_0), "v"(a2_0),
          "v"(b1f[0]), "v"(b1f[1]), "v"(b1f[2]), "v"(b1f[3]),
          "v"(b2f[0]), "v"(b2f[1]), "v"(b2f[2]), "v"(b2f[3]), "v"(cz));

    const float m0 = max16(d0);
    const float m1 = max16(d1);
    const float m2 = max16(d2);
    const float m3 = max16(d3);
    bi[0] = (m0 > bs[0]) ? ct : bi[0];  bs[0] = fmaxf(bs[0], m0);
    bi[1] = (m1 > bs[1]) ? ct : bi[1];  bs[1] = fmaxf(bs[1], m1);
    bi[2] = (m2 > bs[2]) ? ct : bi[2];  bs[2] = fmaxf(bs[2], m2);
    bi[3] = (m3 > bs[3]) ? ct : bi[3];  bs[3] = fmaxf(bs[3], m3);

    a1_0 = a1_1; a2_0 = a2_1;           // rotate pipeline
    a1_1 = na1;  a2_1 = na2;
  }

#pragma unroll
  for (int t = 0; t < 4; ++t) {
    unsigned long long key =
        ((unsigned long long)enc_ord(bs[t]) << 32) | (unsigned int)(~bi[t]);
    unsigned long long o = __shfl_xor(key, 32, 64);
    key = (o > key) ? o : key;          // merge the two kg half-sets of a row
    if (lane < 32) atomicMax(&best[(size_t)rowbase + t * 32 + l31], key);
  }
}

// 256 blocks x 4 waves; wave handles 8 rows of its 32-row tile: re-run the
// bit-identical MFMA chain on each row's winning tile, find smallest matching
// index, and write the output row (vals + idx) directly.
__global__ __launch_bounds__(256) void e8_resolve(
    const unsigned short* __restrict__ Gb,
    const unsigned short* __restrict__ Xs, const float* __restrict__ G,
    const unsigned long long* __restrict__ best, float* __restrict__ out) {
  const int lane = threadIdx.x & 63;
  const int wave = threadIdx.x >> 6;
  const int kg = lane >> 5, l31 = lane & 31;
  const int rt = blockIdx.x;              // 0..255

  short8 b1, b2;
  {
    const size_t row = (size_t)rt * 32 + l31;
    b1 = *reinterpret_cast<const short8*>(Xs + (row*4 + kg)*8);
    b2 = *reinterpret_cast<const short8*>(Xs + (row*4 + 2 + kg)*8);
  }
  f32x16 cz;
#pragma unroll
  for (int i = 0; i < 16; ++i) cz[i] = 0.0f;

  for (int j = wave * 8; j < wave * 8 + 8; ++j) {
    const int srow = rt * 32 + j;
    const unsigned long long k = best[srow];
    const float sstar = dec_ord((unsigned int)(k >> 32));
    const int twin = (int)(~(unsigned int)(k & 0xFFFFFFFFull));

    const unsigned short* ga = Gb + (size_t)twin * 512 + (size_t)l31 * 16;
    short8 a1 = *reinterpret_cast<const short8*>(ga);
    short8 a2 = *reinterpret_cast<const short8*>(ga + (kg << 3));
    f32x16 d = __builtin_amdgcn_mfma_f32_32x32x16_bf16(a1, b1, cz, 0, 0, 0);
    d = __builtin_amdgcn_mfma_f32_32x32x16_bf16(a2, b2, d, 0, 0, 0);

    const int base = twin * 32 + 4 * kg;
    int cand = 0x7FFFFFFF;
#pragma unroll
    for (int r = 15; r >= 0; --r)       // descending -> smallest slot wins
      cand = (d[r] == sstar) ? (base + ((r & 3) + 8 * (r >> 2))) : cand;
    if (l31 != j) cand = 0x7FFFFFFF;    // only this row's two lanes count
    const int o = __shfl_xor(cand, 32, 64);
    cand = min(cand, o);
    if (lane == j) {                    // kg=0 owner lane writes the row
      const float4* g = reinterpret_cast<const float4*>(G + (size_t)cand * 8);
      float4 v0 = g[0], v1 = g[1];
      float4* od = reinterpret_cast<float4*>(out + (size_t)srow * 8);
      od[0] = v0; od[1] = v1;
      out[(size_t)NROWS * 8 + srow] = (float)(cand - 32768);
    }
  }
}

extern "C" void kernel_launch(void* const* d_in, const int* in_sizes, int n_in,
                              void* d_out, int out_size, void* d_ws, size_t ws_size,
                              hipStream_t stream) {
  const float* X  = (const float*)d_in[0];
  const float* G  = (const float*)d_in[1];
  const float* GN = (const float*)d_in[2];
  float* out = (float*)d_out;

  char* ws = (char*)d_ws;
  unsigned short*     Gb   = (unsigned short*)(ws + OFF_GB);
  unsigned short*     Xs   = (unsigned short*)(ws + OFF_XS);
  unsigned long long* best = (unsigned long long*)(ws + OFF_BK);

  e8_prep<<<(NCWP + NROWS + 255) / 256, 256, 0, stream>>>(X, G, GN, Gb, Xs, best);
  e8_main<<<dim3(RBLK, NCHUNK), 256, 0, stream>>>(Gb, Xs, best);
  e8_resolve<<<256, 256, 0, stream>>>(Gb, Xs, G, best, out);
}